// Round 6
// baseline (339.049 us; speedup 1.0000x reference)
//
#include <hip/hip_runtime.h>
#include <hip/hip_bf16.h>

#define B_    2
#define H_    16
#define HKV_  4
#define SQ_   1024
#define SP_   1024
#define SK_   2048
#define D_    128
#define QBLK  64
#define KVBLK 64

typedef __attribute__((ext_vector_type(8))) __bf16 bf16x8;
typedef __attribute__((ext_vector_type(4))) __bf16 bf16x4;
typedef __attribute__((ext_vector_type(4))) float  f32x4;

__device__ inline __bf16 f2bf(float f) { return (__bf16)f; }

// SPLIT=1: 1024 attn blocks (2 KV-halves per (b,h,qt)) writing partials to ws.
// SPLIT=0: 512 attn blocks writing Out directly (R4 fallback, no ws needed).
template<int SPLIT>
__global__ __launch_bounds__(256, 4)
void attn_fused_kernel(const float* __restrict__ Q, const float* __restrict__ Kin,
                       const float* __restrict__ Vin, const float* __restrict__ PK,
                       const float* __restrict__ PV, float* __restrict__ Out,
                       float* __restrict__ opk, float* __restrict__ opv,
                       float* __restrict__ wsO, float* __restrict__ wsML)
{
    // Linear layouts + XOR swizzle (byte ^= (row&7)<<4) on write AND read.
    __shared__ __align__(16) __bf16 Klds[KVBLK * D_];     // [64 k][128 d], 16 KB
    __shared__ __align__(16) __bf16 Vlds[D_ * KVBLK];     // [128 d][64 k], 16 KB
    __shared__ __align__(16) __bf16 Plds[4 * 16 * KVBLK]; // per-wave [16 q][64 k], 8 KB

    const int NATT = SPLIT ? 1024 : 512;
    const int tid = threadIdx.x;
    const int id  = blockIdx.x;

    if (id >= NATT) {
        // ---- fused present_key/present_value copy, XCD-aligned (cid&7 == bgc) ----
        const int cid = id - NATT;             // 0..63
        const int bgc = cid & 7;               // b*4+g
        const int sub = cid >> 3;              // 0..7
        const int isV = sub >> 2;
        const int q4  = sub & 3;
        const int bb = bgc >> 2, g = bgc & 3;
        const float* past = isV ? PV : PK;
        const float* cur  = isV ? Vin : Kin;
        float* dst = isV ? opv : opk;
        const int base = bgc*65536 + q4*16384;
        #pragma unroll 4
        for (int i = 0; i < 64; ++i) {
            int id2 = base + i*256 + tid;
            int d4 = id2 & 31;
            int s  = (id2 >> 5) & (SK_-1);
            const float* srcp = (s < SP_)
                ? past + (((size_t)bgc)*SP_ + s)*(size_t)D_ + d4*4
                : cur  + (((size_t)(bb*H_ + 4*g))*SQ_ + (s - SP_))*(size_t)D_ + d4*4;
            float4 v = *(const float4*)srcp;
            *(float4*)(dst + (size_t)id2*4) = v;
        }
        return;
    }

    // ---- XCD-group swizzle: id%8 == kv_group (b*4 + h>>2) ----
    const int grp  = id & 7;        // b*4 + (h>>2)
    const int rest = id >> 3;
    const int hi   = rest & 3;      // h & 3
    const int qt   = (rest >> 2) & 15;
    const int hf   = SPLIT ? (rest >> 6) : 0;   // KV half
    const int b    = grp >> 2;
    const int h    = (grp & 3)*4 + hi;

    const int lane = tid & 63;
    const int w    = tid >> 6;
    const int lr   = lane & 15;
    const int lg   = lane >> 4;
    const int q0w  = qt * QBLK + w * 16;

    const int nt_full = qt + 17;
    const int ch      = (nt_full + 1) >> 1;
    const int kt_beg  = (SPLIT && hf) ? ch : 0;
    const int kt_end  = SPLIT ? (hf ? nt_full : ch) : nt_full;

    const float scale_l2e = 0.08838834764831845f * 1.4426950408889634f; // 1/sqrt(128)*log2e

    // ---- Q fragments, pre-scaled (scores land in log2 domain); q-row = lr ----
    bf16x8 qf[4];
    {
        const float* qsrc = Q + (((size_t)b*H_ + h)*SQ_ + q0w + lr)*(size_t)D_ + lg*8;
        #pragma unroll
        for (int c = 0; c < 4; ++c) {
            f32x4 a0 = *(const f32x4*)(qsrc + c*32);
            f32x4 a1 = *(const f32x4*)(qsrc + c*32 + 4);
            bf16x8 f;
            #pragma unroll
            for (int j = 0; j < 4; ++j) {
                f[j]   = f2bf(a0[j] * scale_l2e);
                f[j+4] = f2bf(a1[j] * scale_l2e);
            }
            qf[c] = f;
        }
    }

    f32x4 o[8];   // o[dt][r] = O[q = q0w+lr][d = dt*16 + lg*4 + r]
    #pragma unroll
    for (int i = 0; i < 8; ++i) o[i] = (f32x4){0.f,0.f,0.f,0.f};
    float m_r = -1e30f, l_r = 0.f;

    const size_t pk_base = (((size_t)b*HKV_ + (h>>2))*SP_)*(size_t)D_;
    const size_t kn_base = (((size_t)b*H_   + h     )*SQ_)*(size_t)D_;

    f32x4 kreg[4][2], vreg[2][4];

    auto loadKV = [&](const float* ks, const float* vs) {
        #pragma unroll
        for (int i = 0; i < 4; ++i) {
            int idx = i*256 + tid, row = idx >> 4, c8 = idx & 15;
            kreg[i][0] = *(const f32x4*)(ks + row*D_ + c8*8);
            kreg[i][1] = *(const f32x4*)(ks + row*D_ + c8*8 + 4);
        }
        #pragma unroll
        for (int i = 0; i < 2; ++i) {
            int blk = i*256 + tid, bk = blk & 15, bd = blk >> 4;
            #pragma unroll
            for (int kk = 0; kk < 4; ++kk)
                vreg[i][kk] = *(const f32x4*)(vs + (4*bk+kk)*D_ + bd*4);
        }
    };
    auto srcK = [&](int k) { return (k < SP_) ? PK + pk_base + (size_t)k*D_
                                              : Kin + kn_base + (size_t)(k - SP_)*D_; };
    auto srcV = [&](int k) { return (k < SP_) ? PV + pk_base + (size_t)k*D_
                                              : Vin + kn_base + (size_t)(k - SP_)*D_; };

    // ---- prologue: first tile -> regs ----
    loadKV(srcK(kt_beg*KVBLK), srcV(kt_beg*KVBLK));

    for (int kt = kt_beg; kt < kt_end; ++kt) {
        const int k0 = kt * KVBLK;
        __syncthreads();   // (A) prev compute done with LDS; staged regs complete here

        // ---- staged regs -> LDS (fp32->bf16, swizzled) ----
        #pragma unroll
        for (int i = 0; i < 4; ++i) {
            int idx = i*256 + tid, row = idx >> 4, c8 = idx & 15;
            bf16x8 f;
            #pragma unroll
            for (int j = 0; j < 4; ++j) {
                f[j]   = f2bf(kreg[i][0][j]);
                f[j+4] = f2bf(kreg[i][1][j]);
            }
            int off = (row*256 + c8*16) ^ ((row & 7) << 4);
            *(bf16x8*)((char*)Klds + off) = f;
        }
        #pragma unroll
        for (int i = 0; i < 2; ++i) {
            int blk = i*256 + tid, bk = blk & 15, bd = blk >> 4;
            #pragma unroll
            for (int j = 0; j < 4; ++j) {
                int d = 4*bd + j;
                bf16x4 t;
                t[0]=f2bf(vreg[i][0][j]); t[1]=f2bf(vreg[i][1][j]);
                t[2]=f2bf(vreg[i][2][j]); t[3]=f2bf(vreg[i][3][j]);
                int off = (d*128 + bk*8) ^ ((d & 7) << 4);
                *(bf16x4*)((char*)Vlds + off) = t;
            }
        }
        __syncthreads();   // (B) LDS(kt) ready

        // ---- prefetch next tile -> regs (in flight during compute) ----
        if (kt + 1 < kt_end) {
            const int k1 = k0 + KVBLK;
            loadKV(srcK(k1), srcV(k1));
        }

        // ---- QK^T swapped: lane holds k = n*16+lg*4+r, q = lr ----
        f32x4 s[4];
        #pragma unroll
        for (int n = 0; n < 4; ++n) s[n] = (f32x4){0.f,0.f,0.f,0.f};
        #pragma unroll
        for (int n = 0; n < 4; ++n) {
            #pragma unroll
            for (int c = 0; c < 4; ++c) {
                int off = ((n*16 + lr)*256 + c*64 + lg*16) ^ ((lr & 7) << 4);
                bf16x8 kf = *(const bf16x8*)((char*)Klds + off);
                s[n] = __builtin_amdgcn_mfma_f32_16x16x32_bf16(kf, qf[c], s[n], 0, 0, 0);
            }
        }

        // ---- causal mask ----
        float p[16];
        const bool needmask = (k0 + KVBLK - 1) > (q0w + SP_);
        if (needmask) {
            const int qv = q0w + lr + SP_;
            #pragma unroll
            for (int n = 0; n < 4; ++n)
                #pragma unroll
                for (int r = 0; r < 4; ++r) {
                    int kg = k0 + n*16 + lg*4 + r;
                    p[n*4+r] = (kg <= qv) ? s[n][r] : -1e30f;
                }
        } else {
            #pragma unroll
            for (int n = 0; n < 4; ++n)
                #pragma unroll
                for (int r = 0; r < 4; ++r) p[n*4+r] = s[n][r];
        }

        // ---- online softmax with defer-max (T13, THR=8 in log2 domain) ----
        float mx = p[0];
        #pragma unroll
        for (int i = 1; i < 16; ++i) mx = fmaxf(mx, p[i]);
        mx = fmaxf(mx, __shfl_xor(mx, 16));
        mx = fmaxf(mx, __shfl_xor(mx, 32));
        if (!__all(mx <= m_r + 8.0f)) {
            float mnew  = fmaxf(m_r, mx);
            float alpha = exp2f(m_r - mnew);
            m_r = mnew;
            l_r *= alpha;
            #pragma unroll
            for (int dt = 0; dt < 8; ++dt) {
                o[dt][0] *= alpha; o[dt][1] *= alpha;
                o[dt][2] *= alpha; o[dt][3] *= alpha;
            }
        }
        float psum = 0.f;
        #pragma unroll
        for (int i = 0; i < 16; ++i) { p[i] = exp2f(p[i] - m_r); psum += p[i]; }
        psum += __shfl_xor(psum, 16);
        psum += __shfl_xor(psum, 32);
        l_r += psum;

        // ---- P -> per-wave LDS (swizzled) ----
        char* Pw = (char*)Plds + w*2048;
        #pragma unroll
        for (int n = 0; n < 4; ++n) {
            bf16x4 t;
            t[0]=f2bf(p[n*4+0]); t[1]=f2bf(p[n*4+1]);
            t[2]=f2bf(p[n*4+2]); t[3]=f2bf(p[n*4+3]);
            int off = (lr*128 + n*32 + lg*8) ^ ((lr & 7) << 4);
            *(bf16x4*)(Pw + off) = t;
        }

        // ---- PV swapped: O^T[d][q] += mfma(V, P) ----
        #pragma unroll
        for (int kk = 0; kk < 2; ++kk) {
            int poff = (lr*128 + kk*64 + lg*16) ^ ((lr & 7) << 4);
            bf16x8 pa = *(const bf16x8*)(Pw + poff);
            #pragma unroll
            for (int dt = 0; dt < 8; ++dt) {
                int voff = ((dt*16 + lr)*128 + kk*64 + lg*16) ^ ((lr & 7) << 4);
                bf16x8 vf = *(const bf16x8*)((char*)Vlds + voff);
                o[dt] = __builtin_amdgcn_mfma_f32_16x16x32_bf16(vf, pa, o[dt], 0, 0, 0);
            }
        }
    }

    if (SPLIT) {
        // ---- epilogue: unnormalized partial -> ws ----
        const int p_  = ((b*H_ + h) << 4) + qt;     // 0..511
        const int slot = p_*2 + hf;
        float* Oh = wsO + (size_t)slot*8192 + (w*16 + lr)*128;
        #pragma unroll
        for (int dt = 0; dt < 8; ++dt)
            *(f32x4*)(Oh + dt*16 + lg*4) = o[dt];
        if (lg == 0) {
            wsML[slot*128 + (w*16 + lr)*2]     = m_r;
            wsML[slot*128 + (w*16 + lr)*2 + 1] = l_r;
        }
    } else {
        float inv = 1.0f / l_r;
        float* orow = Out + (((size_t)b*H_ + h)*SQ_ + q0w + lr)*(size_t)D_;
        #pragma unroll
        for (int dt = 0; dt < 8; ++dt) {
            f32x4 st;
            st[0]=o[dt][0]*inv; st[1]=o[dt][1]*inv;
            st[2]=o[dt][2]*inv; st[3]=o[dt][3]*inv;
            *(f32x4*)(orow + dt*16 + lg*4) = st;
        }
    }
}

__global__ __launch_bounds__(256)
void combine_kernel(const float* __restrict__ wsO, const float* __restrict__ wsML,
                    float* __restrict__ Out)
{
    const int p   = blockIdx.x;            // (b*16+h)*16 + qt, 0..511
    const int tid = threadIdx.x;
    __shared__ float sml[64][2];
    if (tid < 64) {
        int s0 = (p*2    )*128 + tid*2;
        int s1 = (p*2 + 1)*128 + tid*2;
        float m1 = wsML[s0], l1 = wsML[s0+1];
        float m2 = wsML[s1], l2 = wsML[s1+1];
        float m  = fmaxf(m1, m2);
        float a1 = exp2f(m1 - m), a2 = exp2f(m2 - m);
        float inv = 1.0f / (l1*a1 + l2*a2);
        sml[tid][0] = a1 * inv;
        sml[tid][1] = a2 * inv;
    }
    __syncthreads();
    const float* O1 = wsO + (size_t)(p*2    )*8192;
    const float* O2 = wsO + (size_t)(p*2 + 1)*8192;
    float* dst = Out + (size_t)p*8192;
    #pragma unroll
    for (int i = 0; i < 8; ++i) {
        int v = i*256 + tid;               // f32x4 index, 0..2047
        int row = v >> 5;
        f32x4 x1 = *(const f32x4*)(O1 + v*4);
        f32x4 x2 = *(const f32x4*)(O2 + v*4);
        float a1 = sml[row][0], a2 = sml[row][1];
        f32x4 r;
        r[0]=x1[0]*a1+x2[0]*a2; r[1]=x1[1]*a1+x2[1]*a2;
        r[2]=x1[2]*a1+x2[2]*a2; r[3]=x1[3]*a1+x2[3]*a2;
        *(f32x4*)(dst + v*4) = r;
    }
}

extern "C" void kernel_launch(void* const* d_in, const int* in_sizes, int n_in,
                              void* d_out, int out_size, void* d_ws, size_t ws_size,
                              hipStream_t stream) {
    const float* Q   = (const float*)d_in[0];
    const float* K   = (const float*)d_in[1];
    const float* V   = (const float*)d_in[2];
    const float* PK  = (const float*)d_in[3];
    const float* PV  = (const float*)d_in[4];
    float* out = (float*)d_out;
    float* opk = out + (size_t)B_*H_*SQ_*D_;
    float* opv = opk + (size_t)B_*HKV_*SK_*D_;

    const size_t NEED = (size_t)1024*8192*4 + (size_t)1024*128*4;  // 34 MB
    if (ws_size >= NEED) {
        float* wsO  = (float*)d_ws;
        float* wsML = wsO + (size_t)1024*8192;
        attn_fused_kernel<1><<<1088, 256, 0, stream>>>(Q, K, V, PK, PV, out, opk, opv, wsO, wsML);
        combine_kernel<<<512, 256, 0, stream>>>(wsO, wsML, out);
    } else {
        attn_fused_kernel<0><<<576, 256, 0, stream>>>(Q, K, V, PK, PV, out, opk, opv, nullptr, nullptr);
    }
}

// Round 7
// 84.608 us; speedup vs baseline: 4.0073x; 4.0073x over previous
//
#include <hip/hip_runtime.h>
#include <hip/hip_bf16.h>

#define B_    2
#define H_    16
#define HKV_  4
#define SQ_   1024
#define SP_   1024
#define SK_   2048
#define D_    128
#define QBLK  128
#define KVBLK 64
#define NTHR  512

typedef __attribute__((ext_vector_type(8))) __bf16 bf16x8;
typedef __attribute__((ext_vector_type(4))) __bf16 bf16x4;
typedef __attribute__((ext_vector_type(4))) float  f32x4;

__device__ inline __bf16 f2bf(float f) { return (__bf16)f; }

// SPLIT=1: 512 attn blocks (2 KV halves per (b,h,qt)), partials to ws + combine.
// SPLIT=0: 256 attn blocks writing Out directly (fallback when ws too small).
template<int SPLIT>
__global__ __launch_bounds__(NTHR, 2)
void attn_fused_kernel(const float* __restrict__ Q, const float* __restrict__ Kin,
                       const float* __restrict__ Vin, const float* __restrict__ PK,
                       const float* __restrict__ PV, float* __restrict__ Out,
                       float* __restrict__ opk, float* __restrict__ opv,
                       float* __restrict__ wsO, float* __restrict__ wsML)
{
    // Linear layouts + XOR swizzle (byte ^= (row&7)<<4) on write AND read.
    __shared__ __align__(16) __bf16 Klds[KVBLK * D_];     // [64 k][128 d], 16 KB
    __shared__ __align__(16) __bf16 Vlds[D_ * KVBLK];     // [128 d][64 k], 16 KB
    __shared__ __align__(16) __bf16 Plds[8 * 16 * KVBLK]; // per-wave [16 q][64 k], 16 KB

    const int tid = threadIdx.x;
    const int id  = blockIdx.x;

    if (id < 64) {
        // ---- fused present copy, XCD-aligned (id&7 == bgc), dispatched FIRST ----
        const int cid = id;
        const int bgc = cid & 7;               // b*4+g
        const int sub = cid >> 3;              // 0..7
        const int isV = sub >> 2;
        const int q4  = sub & 3;
        const int bb = bgc >> 2, g = bgc & 3;
        const float* past = isV ? PV : PK;
        const float* cur  = isV ? Vin : Kin;
        float* dst = isV ? opv : opk;
        const int base = bgc*65536 + q4*16384;
        #pragma unroll 4
        for (int i = 0; i < 32; ++i) {
            int id2 = base + i*NTHR + tid;
            int d4 = id2 & 31;
            int s  = (id2 >> 5) & (SK_-1);
            const float* srcp = (s < SP_)
                ? past + (((size_t)bgc)*SP_ + s)*(size_t)D_ + d4*4
                : cur  + (((size_t)(bb*H_ + 4*g))*SQ_ + (s - SP_))*(size_t)D_ + d4*4;
            float4 v = *(const float4*)srcp;
            *(float4*)(dst + (size_t)id2*4) = v;
        }
        return;
    }

    // ---- attn blocks: XCD-group swizzle (aid%8 == kv_group), LPT (long qt first) ----
    const int aid  = id - 64;
    const int grp  = aid & 7;        // b*4 + (h>>2)
    const int rest = aid >> 3;
    const int hf   = SPLIT ? (rest & 1) : 0;
    const int hi   = SPLIT ? ((rest >> 1) & 3) : (rest & 3);
    const int qt   = 7 - (SPLIT ? (rest >> 3) : (rest >> 2));   // longest first
    const int b    = grp >> 2;
    const int h    = (grp & 3)*4 + hi;

    const int lane = tid & 63;
    const int w    = tid >> 6;       // 0..7
    const int lr   = lane & 15;
    const int lg   = lane >> 4;
    const int q0w  = qt * QBLK + w * 16;

    const int nt_full = 2*qt + 18;
    const int ch      = qt + 9;                       // equal halves
    const int kt_beg  = (SPLIT && hf) ? ch : 0;
    const int kt_end  = SPLIT ? (hf ? nt_full : ch) : nt_full;

    const float scale_l2e = 0.08838834764831845f * 1.4426950408889634f; // 1/sqrt(128)*log2e

    // ---- Q fragments, pre-scaled; q-row = lr ----
    bf16x8 qf[4];
    {
        const float* qsrc = Q + (((size_t)b*H_ + h)*SQ_ + q0w + lr)*(size_t)D_ + lg*8;
        #pragma unroll
        for (int c = 0; c < 4; ++c) {
            f32x4 a0 = *(const f32x4*)(qsrc + c*32);
            f32x4 a1 = *(const f32x4*)(qsrc + c*32 + 4);
            bf16x8 f;
            #pragma unroll
            for (int j = 0; j < 4; ++j) {
                f[j]   = f2bf(a0[j] * scale_l2e);
                f[j+4] = f2bf(a1[j] * scale_l2e);
            }
            qf[c] = f;
        }
    }

    f32x4 o[8];   // o[dt][r] = O[q = q0w+lr][d = dt*16 + lg*4 + r]
    #pragma unroll
    for (int i = 0; i < 8; ++i) o[i] = (f32x4){0.f,0.f,0.f,0.f};
    float m_r = -1e30f, l_r = 0.f;

    const size_t pk_base = (((size_t)b*HKV_ + (h>>2))*SP_)*(size_t)D_;
    const size_t kn_base = (((size_t)b*H_   + h     )*SQ_)*(size_t)D_;

    f32x4 kreg[2][2], vreg[4];

    auto loadKV = [&](const float* ks, const float* vs) {
        #pragma unroll
        for (int i = 0; i < 2; ++i) {
            int idx = i*NTHR + tid, row = idx >> 4, c8 = idx & 15;
            kreg[i][0] = *(const f32x4*)(ks + row*D_ + c8*8);
            kreg[i][1] = *(const f32x4*)(ks + row*D_ + c8*8 + 4);
        }
        {
            int bk = tid & 15, bd = tid >> 4;   // bd 0..31
            #pragma unroll
            for (int kk = 0; kk < 4; ++kk)
                vreg[kk] = *(const f32x4*)(vs + (4*bk+kk)*D_ + bd*4);
        }
    };
    auto srcK = [&](int k) { return (k < SP_) ? PK + pk_base + (size_t)k*D_
                                              : Kin + kn_base + (size_t)(k - SP_)*D_; };
    auto srcV = [&](int k) { return (k < SP_) ? PV + pk_base + (size_t)k*D_
                                              : Vin + kn_base + (size_t)(k - SP_)*D_; };

    // ---- prologue: first tile -> regs ----
    loadKV(srcK(kt_beg*KVBLK), srcV(kt_beg*KVBLK));

    for (int kt = kt_beg; kt < kt_end; ++kt) {
        const int k0 = kt * KVBLK;
        __syncthreads();   // (A) prev compute done with LDS; staged regs complete

        // ---- staged regs -> LDS (fp32->bf16, swizzled) ----
        #pragma unroll
        for (int i = 0; i < 2; ++i) {
            int idx = i*NTHR + tid, row = idx >> 4, c8 = idx & 15;
            bf16x8 f;
            #pragma unroll
            for (int j = 0; j < 4; ++j) {
                f[j]   = f2bf(kreg[i][0][j]);
                f[j+4] = f2bf(kreg[i][1][j]);
            }
            int off = (row*256 + c8*16) ^ ((row & 7) << 4);
            *(bf16x8*)((char*)Klds + off) = f;
        }
        {
            int bk = tid & 15, bd = tid >> 4;
            #pragma unroll
            for (int j = 0; j < 4; ++j) {
                int d = 4*bd + j;
                bf16x4 t;
                t[0]=f2bf(vreg[0][j]); t[1]=f2bf(vreg[1][j]);
                t[2]=f2bf(vreg[2][j]); t[3]=f2bf(vreg[3][j]);
                int off = (d*128 + bk*8) ^ ((d & 7) << 4);
                *(bf16x4*)((char*)Vlds + off) = t;
            }
        }
        __syncthreads();   // (B) LDS(kt) ready

        // ---- prefetch next tile -> regs (in flight during compute) ----
        if (kt + 1 < kt_end) {
            const int k1 = k0 + KVBLK;
            loadKV(srcK(k1), srcV(k1));
        }

        // ---- QK^T swapped: lane holds k = n*16+lg*4+r, q = lr ----
        f32x4 s[4];
        #pragma unroll
        for (int n = 0; n < 4; ++n) s[n] = (f32x4){0.f,0.f,0.f,0.f};
        #pragma unroll
        for (int n = 0; n < 4; ++n) {
            #pragma unroll
            for (int c = 0; c < 4; ++c) {
                int off = ((n*16 + lr)*256 + c*64 + lg*16) ^ ((lr & 7) << 4);
                bf16x8 kf = *(const bf16x8*)((char*)Klds + off);
                s[n] = __builtin_amdgcn_mfma_f32_16x16x32_bf16(kf, qf[c], s[n], 0, 0, 0);
            }
        }

        // ---- causal mask (per-wave) ----
        float p[16];
        const bool needmask = (k0 + KVBLK - 1) > (q0w + SP_);
        if (needmask) {
            const int qv = q0w + lr + SP_;
            #pragma unroll
            for (int n = 0; n < 4; ++n)
                #pragma unroll
                for (int r = 0; r < 4; ++r) {
                    int kg = k0 + n*16 + lg*4 + r;
                    p[n*4+r] = (kg <= qv) ? s[n][r] : -1e30f;
                }
        } else {
            #pragma unroll
            for (int n = 0; n < 4; ++n)
                #pragma unroll
                for (int r = 0; r < 4; ++r) p[n*4+r] = s[n][r];
        }

        // ---- online softmax with defer-max (T13, THR=8, log2 domain) ----
        float mx = p[0];
        #pragma unroll
        for (int i = 1; i < 16; ++i) mx = fmaxf(mx, p[i]);
        mx = fmaxf(mx, __shfl_xor(mx, 16));
        mx = fmaxf(mx, __shfl_xor(mx, 32));
        if (!__all(mx <= m_r + 8.0f)) {
            float mnew  = fmaxf(m_r, mx);
            float alpha = exp2f(m_r - mnew);
            m_r = mnew;
            l_r *= alpha;
            #pragma unroll
            for (int dt = 0; dt < 8; ++dt) {
                o[dt][0] *= alpha; o[dt][1] *= alpha;
                o[dt][2] *= alpha; o[dt][3] *= alpha;
            }
        }
        float psum = 0.f;
        #pragma unroll
        for (int i = 0; i < 16; ++i) { p[i] = exp2f(p[i] - m_r); psum += p[i]; }
        psum += __shfl_xor(psum, 16);
        psum += __shfl_xor(psum, 32);
        l_r += psum;

        // ---- P -> per-wave LDS (swizzled) ----
        char* Pw = (char*)Plds + w*2048;
        #pragma unroll
        for (int n = 0; n < 4; ++n) {
            bf16x4 t;
            t[0]=f2bf(p[n*4+0]); t[1]=f2bf(p[n*4+1]);
            t[2]=f2bf(p[n*4+2]); t[3]=f2bf(p[n*4+3]);
            int off = (lr*128 + n*32 + lg*8) ^ ((lr & 7) << 4);
            *(bf16x4*)(Pw + off) = t;
        }

        // ---- PV swapped: O^T[d][q] += mfma(V, P) ----
        #pragma unroll
        for (int kk = 0; kk < 2; ++kk) {
            int poff = (lr*128 + kk*64 + lg*16) ^ ((lr & 7) << 4);
            bf16x8 pa = *(const bf16x8*)(Pw + poff);
            #pragma unroll
            for (int dt = 0; dt < 8; ++dt) {
                int voff = ((dt*16 + lr)*128 + kk*64 + lg*16) ^ ((lr & 7) << 4);
                bf16x8 vf = *(const bf16x8*)((char*)Vlds + voff);
                o[dt] = __builtin_amdgcn_mfma_f32_16x16x32_bf16(vf, pa, o[dt], 0, 0, 0);
            }
        }
    }

    if (SPLIT) {
        // ---- unnormalized partial -> ws ----
        const int p_   = ((b*H_ + h) << 3) + qt;     // 0..255
        const int slot = p_*2 + hf;
        float* Oh = wsO + (size_t)slot*16384 + (size_t)(w*16 + lr)*128;
        #pragma unroll
        for (int dt = 0; dt < 8; ++dt)
            *(f32x4*)(Oh + dt*16 + lg*4) = o[dt];
        if (lg == 0) {
            wsML[(size_t)slot*256 + (w*16 + lr)*2]     = m_r;
            wsML[(size_t)slot*256 + (w*16 + lr)*2 + 1] = l_r;
        }
    } else {
        float inv = 1.0f / l_r;
        float* orow = Out + (((size_t)b*H_ + h)*SQ_ + q0w + lr)*(size_t)D_;
        #pragma unroll
        for (int dt = 0; dt < 8; ++dt) {
            f32x4 st;
            st[0]=o[dt][0]*inv; st[1]=o[dt][1]*inv;
            st[2]=o[dt][2]*inv; st[3]=o[dt][3]*inv;
            *(f32x4*)(orow + dt*16 + lg*4) = st;
        }
    }
}

__global__ __launch_bounds__(256)
void combine_kernel(const float* __restrict__ wsO, const float* __restrict__ wsML,
                    float* __restrict__ Out)
{
    const int p   = blockIdx.x;            // (b*16+h)*8 + qt, 0..255 (128 q-rows each)
    const int tid = threadIdx.x;
    __shared__ float sml[128][2];
    if (tid < 128) {
        size_t s0 = (size_t)(p*2    )*256 + tid*2;
        size_t s1 = (size_t)(p*2 + 1)*256 + tid*2;
        float m1 = wsML[s0], l1 = wsML[s0+1];
        float m2 = wsML[s1], l2 = wsML[s1+1];
        float m  = fmaxf(m1, m2);
        float a1 = exp2f(m1 - m), a2 = exp2f(m2 - m);
        float inv = 1.0f / (l1*a1 + l2*a2);
        sml[tid][0] = a1 * inv;
        sml[tid][1] = a2 * inv;
    }
    __syncthreads();
    const float* O1 = wsO + (size_t)(p*2    )*16384;
    const float* O2 = wsO + (size_t)(p*2 + 1)*16384;
    float* dst = Out + (size_t)p*16384;
    #pragma unroll
    for (int i = 0; i < 16; ++i) {
        int v = i*256 + tid;               // f32x4 index, 0..4095
        int row = v >> 5;                  // 32 f32x4 per 128-wide row
        f32x4 x1 = *(const f32x4*)(O1 + (size_t)v*4);
        f32x4 x2 = *(const f32x4*)(O2 + (size_t)v*4);
        float a1 = sml[row][0], a2 = sml[row][1];
        f32x4 r;
        r[0]=x1[0]*a1+x2[0]*a2; r[1]=x1[1]*a1+x2[1]*a2;
        r[2]=x1[2]*a1+x2[2]*a2; r[3]=x1[3]*a1+x2[3]*a2;
        *(f32x4*)(dst + (size_t)v*4) = r;
    }
}

extern "C" void kernel_launch(void* const* d_in, const int* in_sizes, int n_in,
                              void* d_out, int out_size, void* d_ws, size_t ws_size,
                              hipStream_t stream) {
    const float* Q   = (const float*)d_in[0];
    const float* K   = (const float*)d_in[1];
    const float* V   = (const float*)d_in[2];
    const float* PK  = (const float*)d_in[3];
    const float* PV  = (const float*)d_in[4];
    float* out = (float*)d_out;
    float* opk = out + (size_t)B_*H_*SQ_*D_;
    float* opv = opk + (size_t)B_*HKV_*SK_*D_;

    const size_t NEED = (size_t)512*16384*4 + (size_t)512*256*4;  // ~34 MB
    if (ws_size >= NEED) {
        float* wsO  = (float*)d_ws;
        float* wsML = wsO + (size_t)512*16384;
        attn_fused_kernel<1><<<576, NTHR, 0, stream>>>(Q, K, V, PK, PV, out, opk, opv, wsO, wsML);
        combine_kernel<<<256, 256, 0, stream>>>(wsO, wsML, out);
    } else {
        attn_fused_kernel<0><<<320, NTHR, 0, stream>>>(Q, K, V, PK, PV, out, opk, opv, nullptr, nullptr);
    }
}

// Round 8
// 82.763 us; speedup vs baseline: 4.0966x; 1.0223x over previous
//
#include <hip/hip_runtime.h>
#include <hip/hip_bf16.h>

#define B_    2
#define H_    16
#define HKV_  4
#define SQ_   1024
#define SP_   1024
#define SK_   2048
#define D_    128
#define QBLK  64
#define KVBLK 64
#define TILEB 32768       // ws tile: 16KB K + 16KB Vt (bf16, pre-swizzled LDS image)
#define NPAST 128         // 8 groups x 16 past tiles
#define NTILES 640        // + 32 heads x 16 new tiles

typedef __attribute__((ext_vector_type(8))) __bf16 bf16x8;
typedef __attribute__((ext_vector_type(4))) __bf16 bf16x4;
typedef __attribute__((ext_vector_type(4))) float  f32x4;

__device__ inline __bf16 f2bf(float f) { return (__bf16)f; }

__device__ inline void gl_lds16(const char* g, char* l) {
    __builtin_amdgcn_global_load_lds(
        (const __attribute__((address_space(1))) void*)g,
        (__attribute__((address_space(3))) void*)l, 16, 0, 0);
}

// ---- prep: present_key/value copy + bf16/swizzled tile build (once per KV tile) ----
__global__ __launch_bounds__(256)
void prep_kernel(const float* __restrict__ Kin, const float* __restrict__ Vin,
                 const float* __restrict__ PK,  const float* __restrict__ PV,
                 float* __restrict__ opk, float* __restrict__ opv, char* __restrict__ ws)
{
    __shared__ __align__(16) char Tl[TILEB];
    const int tid = threadIdx.x;
    const int id  = blockIdx.x;        // 0..639

    const float *ksrc, *vsrc;
    float *pkdst = nullptr, *pvdst = nullptr;
    size_t tidx;
    if (id < NPAST) {
        int grp = id & 7, kt = id >> 3;            // past tile kt 0..15
        int s0 = kt * 64;
        ksrc = PK + (((size_t)grp)*SP_ + s0)*(size_t)D_;
        vsrc = PV + (((size_t)grp)*SP_ + s0)*(size_t)D_;
        pkdst = opk + (((size_t)grp)*SK_ + s0)*(size_t)D_;
        pvdst = opv + (((size_t)grp)*SK_ + s0)*(size_t)D_;
        tidx = (size_t)(grp*16 + kt);
    } else {
        int nid = id - NPAST;
        int h16 = nid >> 4;                        // b*16+h
        int ktp = nid & 15;
        int bb = h16 >> 4, hh = h16 & 15;
        int s0 = ktp * 64;
        ksrc = Kin + (((size_t)h16)*SQ_ + s0)*(size_t)D_;
        vsrc = Vin + (((size_t)h16)*SQ_ + s0)*(size_t)D_;
        if ((hh & 3) == 0) {                       // heads 0,4,8,12 feed present
            int grp = bb*4 + (hh >> 2);
            pkdst = opk + (((size_t)grp)*SK_ + SP_ + s0)*(size_t)D_;
            pvdst = opv + (((size_t)grp)*SK_ + SP_ + s0)*(size_t)D_;
        }
        tidx = (size_t)(NPAST + nid);
    }

    // K rows: coalesced read -> present copy + bf16 swizzled stage (R4's exact layout)
    #pragma unroll
    for (int i = 0; i < 4; ++i) {
        int idx = i*256 + tid, row = idx >> 4, c8 = idx & 15;
        f32x4 a0 = *(const f32x4*)(ksrc + row*D_ + c8*8);
        f32x4 a1 = *(const f32x4*)(ksrc + row*D_ + c8*8 + 4);
        if (pkdst) {
            *(f32x4*)(pkdst + row*D_ + c8*8)     = a0;
            *(f32x4*)(pkdst + row*D_ + c8*8 + 4) = a1;
        }
        bf16x8 f;
        #pragma unroll
        for (int j = 0; j < 4; ++j) { f[j] = f2bf(a0[j]); f[j+4] = f2bf(a1[j]); }
        int off = (row*256 + c8*16) ^ ((row & 7) << 4);
        *(bf16x8*)(Tl + off) = f;
    }
    // V: transpose-stage into Tl[16K..32K) (R4's exact Vt layout)
    #pragma unroll
    for (int i = 0; i < 2; ++i) {
        int blk = i*256 + tid, bk = blk & 15, bd = blk >> 4;
        f32x4 vr[4];
        #pragma unroll
        for (int kk = 0; kk < 4; ++kk)
            vr[kk] = *(const f32x4*)(vsrc + (4*bk+kk)*D_ + bd*4);
        #pragma unroll
        for (int j = 0; j < 4; ++j) {
            int d = 4*bd + j;
            bf16x4 t;
            t[0]=f2bf(vr[0][j]); t[1]=f2bf(vr[1][j]);
            t[2]=f2bf(vr[2][j]); t[3]=f2bf(vr[3][j]);
            int off = (d*128 + bk*8) ^ ((d & 7) << 4);
            *(bf16x4*)(Tl + 16384 + off) = t;
        }
    }
    // present_value: coalesced re-read (L1/L2-hot)
    if (pvdst) {
        #pragma unroll
        for (int i = 0; i < 4; ++i) {
            int idx = i*256 + tid, row = idx >> 4, c8 = idx & 15;
            *(f32x4*)(pvdst + row*D_ + c8*8)     = *(const f32x4*)(vsrc + row*D_ + c8*8);
            *(f32x4*)(pvdst + row*D_ + c8*8 + 4) = *(const f32x4*)(vsrc + row*D_ + c8*8 + 4);
        }
    }
    __syncthreads();
    // LDS image -> ws (byte-identical)
    char* dst = ws + tidx*TILEB;
    #pragma unroll
    for (int i = 0; i < 8; ++i) {
        int off = i*4096 + tid*16;
        *(f32x4*)(dst + off) = *(const f32x4*)(Tl + off);
    }
}

// ---- lean attention: gload_lds double-buffer, raw barriers + counted vmcnt ----
__global__ __launch_bounds__(256, 2)
void attn_lean_kernel(const float* __restrict__ Q, float* __restrict__ Out,
                      const char* __restrict__ ws)
{
    __shared__ __align__(16) char Kb2[2][16384];
    __shared__ __align__(16) char Vb2[2][16384];
    __shared__ __align__(16) char Pl[8192];

    const int tid = threadIdx.x;
    const int id  = blockIdx.x;        // 0..511
    const int grp  = id & 7;           // b*4 + (h>>2): XCD-aligned KV group
    const int rest = id >> 3;
    const int hi   = rest & 3;
    const int qt   = rest >> 2;        // 0..15
    const int b    = grp >> 2;
    const int h    = (grp & 3)*4 + hi;
    const int h16  = b*16 + h;

    const int lane = tid & 63;
    const int w    = tid >> 6;
    const int lr   = lane & 15;
    const int lg   = lane >> 4;
    const int q0w  = qt * QBLK + w * 16;
    const int nt   = qt + 17;

    const float scale_l2e = 0.08838834764831845f * 1.4426950408889634f; // 1/sqrt(128)*log2e

    const char* tiles = ws;
    const int boff = w*1024 + lane*16;
    auto STAGE = [&](int buf, int kt) {
        size_t t = (kt < 16) ? (size_t)(grp*16 + kt) : (size_t)(NPAST + h16*16 + (kt - 16));
        const char* src = tiles + t*TILEB;
        char* kb = Kb2[buf];
        char* vb = Vb2[buf];
        #pragma unroll
        for (int i = 0; i < 4; ++i) gl_lds16(src + i*4096 + boff,         kb + i*4096 + w*1024);
        #pragma unroll
        for (int i = 0; i < 4; ++i) gl_lds16(src + 16384 + i*4096 + boff, vb + i*4096 + w*1024);
    };

    STAGE(0, 0);   // DMA for tile 0 starts immediately

    // ---- Q fragments, pre-scaled; q-row = lr ----
    bf16x8 qf[4];
    {
        const float* qsrc = Q + (((size_t)h16)*SQ_ + q0w + lr)*(size_t)D_ + lg*8;
        #pragma unroll
        for (int c = 0; c < 4; ++c) {
            f32x4 a0 = *(const f32x4*)(qsrc + c*32);
            f32x4 a1 = *(const f32x4*)(qsrc + c*32 + 4);
            bf16x8 f;
            #pragma unroll
            for (int j = 0; j < 4; ++j) {
                f[j]   = f2bf(a0[j] * scale_l2e);
                f[j+4] = f2bf(a1[j] * scale_l2e);
            }
            qf[c] = f;
        }
    }

    f32x4 o[8];   // o[dt][r] = O[q = q0w+lr][d = dt*16 + lg*4 + r]
    #pragma unroll
    for (int i = 0; i < 8; ++i) o[i] = (f32x4){0.f,0.f,0.f,0.f};
    float m_r = -1e30f, l_r = 0.f;

    for (int kt = 0; kt < nt; ++kt) {
        const int cur = kt & 1;
        // issue next tile's DMA, then wait ONLY for current tile (8 loads stay in flight)
        if (kt + 1 < nt) {
            STAGE(cur ^ 1, kt + 1);
            asm volatile("s_waitcnt vmcnt(8)" ::: "memory");
        } else {
            asm volatile("s_waitcnt vmcnt(0)" ::: "memory");
        }
        __builtin_amdgcn_sched_barrier(0);
        __builtin_amdgcn_s_barrier();        // all waves' tile-kt DMA published
        __builtin_amdgcn_sched_barrier(0);

        const char* Kbp = Kb2[cur];
        const char* Vbp = Vb2[cur];

        // ---- QK^T swapped: lane holds k = n*16+lg*4+r, q = lr ----
        f32x4 s[4];
        #pragma unroll
        for (int n = 0; n < 4; ++n) s[n] = (f32x4){0.f,0.f,0.f,0.f};
        #pragma unroll
        for (int n = 0; n < 4; ++n) {
            #pragma unroll
            for (int c = 0; c < 4; ++c) {
                int off = ((n*16 + lr)*256 + c*64 + lg*16) ^ ((lr & 7) << 4);
                bf16x8 kf = *(const bf16x8*)(Kbp + off);
                s[n] = __builtin_amdgcn_mfma_f32_16x16x32_bf16(kf, qf[c], s[n], 0, 0, 0);
            }
        }

        // ---- causal mask ----
        const int k0 = kt * KVBLK;
        float p[16];
        const bool needmask = (k0 + KVBLK - 1) > (q0w + SP_);
        if (needmask) {
            const int qv = q0w + lr + SP_;
            #pragma unroll
            for (int n = 0; n < 4; ++n)
                #pragma unroll
                for (int r = 0; r < 4; ++r) {
                    int kg = k0 + n*16 + lg*4 + r;
                    p[n*4+r] = (kg <= qv) ? s[n][r] : -1e30f;
                }
        } else {
            #pragma unroll
            for (int n = 0; n < 4; ++n)
                #pragma unroll
                for (int r = 0; r < 4; ++r) p[n*4+r] = s[n][r];
        }

        // ---- online softmax with defer-max (T13, THR=8, log2 domain) ----
        float mx = p[0];
        #pragma unroll
        for (int i = 1; i < 16; ++i) mx = fmaxf(mx, p[i]);
        mx = fmaxf(mx, __shfl_xor(mx, 16));
        mx = fmaxf(mx, __shfl_xor(mx, 32));
        if (!__all(mx <= m_r + 8.0f)) {
            float mnew  = fmaxf(m_r, mx);
            float alpha = exp2f(m_r - mnew);
            m_r = mnew;
            l_r *= alpha;
            #pragma unroll
            for (int dt = 0; dt < 8; ++dt) {
                o[dt][0] *= alpha; o[dt][1] *= alpha;
                o[dt][2] *= alpha; o[dt][3] *= alpha;
            }
        }
        float psum = 0.f;
        #pragma unroll
        for (int i = 0; i < 16; ++i) { p[i] = exp2f(p[i] - m_r); psum += p[i]; }
        psum += __shfl_xor(psum, 16);
        psum += __shfl_xor(psum, 32);
        l_r += psum;

        // ---- P -> per-wave LDS (swizzled; own region, no cross-wave sync) ----
        char* Pw = Pl + w*2048;
        #pragma unroll
        for (int n = 0; n < 4; ++n) {
            bf16x4 t;
            t[0]=f2bf(p[n*4+0]); t[1]=f2bf(p[n*4+1]);
            t[2]=f2bf(p[n*4+2]); t[3]=f2bf(p[n*4+3]);
            int off = (lr*128 + n*32 + lg*8) ^ ((lr & 7) << 4);
            *(bf16x4*)(Pw + off) = t;
        }

        // ---- PV swapped: O^T[d][q] += mfma(V, P) ----
        #pragma unroll
        for (int kk = 0; kk < 2; ++kk) {
            int poff = (lr*128 + kk*64 + lg*16) ^ ((lr & 7) << 4);
            bf16x8 pa = *(const bf16x8*)(Pw + poff);
            #pragma unroll
            for (int dt = 0; dt < 8; ++dt) {
                int voff = ((dt*16 + lr)*128 + kk*64 + lg*16) ^ ((lr & 7) << 4);
                bf16x8 vf = *(const bf16x8*)(Vbp + voff);
                o[dt] = __builtin_amdgcn_mfma_f32_16x16x32_bf16(vf, pa, o[dt], 0, 0, 0);
            }
        }

        __builtin_amdgcn_sched_barrier(0);
        __builtin_amdgcn_s_barrier();        // compute(cur) done; next iter may DMA it
    }

    // ---- epilogue ----
    float inv = 1.0f / l_r;
    float* orow = Out + (((size_t)h16)*SQ_ + q0w + lr)*(size_t)D_;
    #pragma unroll
    for (int dt = 0; dt < 8; ++dt) {
        f32x4 st;
        st[0]=o[dt][0]*inv; st[1]=o[dt][1]*inv;
        st[2]=o[dt][2]*inv; st[3]=o[dt][3]*inv;
        *(f32x4*)(orow + dt*16 + lg*4) = st;
    }
}

// ======== fallback (exact R4 path, used only if ws too small) ========
__global__ __launch_bounds__(256, 2)
void attn_fallback_kernel(const float* __restrict__ Q, const float* __restrict__ Kin,
                          const float* __restrict__ Vin, const float* __restrict__ PK,
                          const float* __restrict__ PV, float* __restrict__ Out,
                          float* __restrict__ opk, float* __restrict__ opv)
{
    __shared__ __align__(16) __bf16 Klds[KVBLK * D_];
    __shared__ __align__(16) __bf16 Vlds[D_ * KVBLK];
    __shared__ __align__(16) __bf16 Plds[4 * 16 * KVBLK];

    const int tid = threadIdx.x;
    const int id  = blockIdx.x;

    if (id >= 512) {
        const int cid = id - 512;
        const int bgc = cid & 7;
        const int sub = cid >> 3;
        const int isV = sub >> 2;
        const int q4  = sub & 3;
        const int bb = bgc >> 2, g = bgc & 3;
        const float* past = isV ? PV : PK;
        const float* cur  = isV ? Vin : Kin;
        float* dst = isV ? opv : opk;
        const int base = bgc*65536 + q4*16384;
        #pragma unroll 4
        for (int i = 0; i < 64; ++i) {
            int id2 = base + i*256 + tid;
            int d4 = id2 & 31;
            int s  = (id2 >> 5) & (SK_-1);
            const float* srcp = (s < SP_)
                ? past + (((size_t)bgc)*SP_ + s)*(size_t)D_ + d4*4
                : cur  + (((size_t)(bb*H_ + 4*g))*SQ_ + (s - SP_))*(size_t)D_ + d4*4;
            float4 v = *(const float4*)srcp;
            *(float4*)(dst + (size_t)id2*4) = v;
        }
        return;
    }

    const int grp  = id & 7;
    const int rest = id >> 3;
    const int hi   = rest & 3;
    const int qt   = rest >> 2;
    const int b    = grp >> 2;
    const int h    = (grp & 3)*4 + hi;

    const int lane = tid & 63;
    const int w    = tid >> 6;
    const int lr   = lane & 15;
    const int lg   = lane >> 4;
    const int q0w  = qt * QBLK + w * 16;

    const float scale_l2e = 0.08838834764831845f * 1.4426950408889634f;

    bf16x8 qf[4];
    {
        const float* qsrc = Q + (((size_t)b*H_ + h)*SQ_ + q0w + lr)*(size_t)D_ + lg*8;
        #pragma unroll
        for (int c = 0; c < 4; ++c) {
            f32x4 a0 = *(const f32x4*)(qsrc + c*32);
            f32x4 a1 = *(const f32x4*)(qsrc + c*32 + 4);
            bf16x8 f;
            #pragma unroll
            for (int j = 0; j < 4; ++j) {
                f[j]   = f2bf(a0[j] * scale_l2e);
                f[j+4] = f2bf(a1[j] * scale_l2e);
            }
            qf[c] = f;
        }
    }

    f32x4 o[8];
    #pragma unroll
    for (int i = 0; i < 8; ++i) o[i] = (f32x4){0.f,0.f,0.f,0.f};
    float m_r = -1e30f, l_r = 0.f;

    const int nt = qt + 17;
    const size_t pk_base = (((size_t)b*HKV_ + (h>>2))*SP_)*(size_t)D_;
    const size_t kn_base = (((size_t)b*H_   + h     )*SQ_)*(size_t)D_;

    f32x4 kreg[4][2], vreg[2][4];
    auto loadKV = [&](const float* ks, const float* vs) {
        #pragma unroll
        for (int i = 0; i < 4; ++i) {
            int idx = i*256 + tid, row = idx >> 4, c8 = idx & 15;
            kreg[i][0] = *(const f32x4*)(ks + row*D_ + c8*8);
            kreg[i][1] = *(const f32x4*)(ks + row*D_ + c8*8 + 4);
        }
        #pragma unroll
        for (int i = 0; i < 2; ++i) {
            int blk = i*256 + tid, bk = blk & 15, bd = blk >> 4;
            #pragma unroll
            for (int kk = 0; kk < 4; ++kk)
                vreg[i][kk] = *(const f32x4*)(vs + (4*bk+kk)*D_ + bd*4);
        }
    };

    loadKV(PK + pk_base, PV + pk_base);

    for (int kt = 0; kt < nt; ++kt) {
        const int k0 = kt * KVBLK;
        __syncthreads();
        #pragma unroll
        for (int i = 0; i < 4; ++i) {
            int idx = i*256 + tid, row = idx >> 4, c8 = idx & 15;
            bf16x8 f;
            #pragma unroll
            for (int j = 0; j < 4; ++j) {
                f[j]   = f2bf(kreg[i][0][j]);
                f[j+4] = f2bf(kreg[i][1][j]);
            }
            int off = (row*256 + c8*16) ^ ((row & 7) << 4);
            *(bf16x8*)((char*)Klds + off) = f;
        }
        #pragma unroll
        for (int i = 0; i < 2; ++i) {
            int blk = i*256 + tid, bk = blk & 15, bd = blk >> 4;
            #pragma unroll
            for (int j = 0; j < 4; ++j) {
                int d = 4*bd + j;
                bf16x4 t;
                t[0]=f2bf(vreg[i][0][j]); t[1]=f2bf(vreg[i][1][j]);
                t[2]=f2bf(vreg[i][2][j]); t[3]=f2bf(vreg[i][3][j]);
                int off = (d*128 + bk*8) ^ ((d & 7) << 4);
                *(bf16x4*)((char*)Vlds + off) = t;
            }
        }
        __syncthreads();

        if (kt + 1 < nt) {
            const int k1 = k0 + KVBLK;
            const float* ks = (k1 < SP_) ? PK + pk_base + (size_t)k1*D_
                                         : Kin + kn_base + (size_t)(k1 - SP_)*D_;
            const float* vs = (k1 < SP_) ? PV + pk_base + (size_t)k1*D_
                                         : Vin + kn_base + (size_t)(k1 - SP_)*D_;
            loadKV(ks, vs);
        }

        f32x4 s[4];
        #pragma unroll
        for (int n = 0; n < 4; ++n) s[n] = (f32x4){0.f,0.f,0.f,0.f};
        #pragma unroll
        for (int n = 0; n < 4; ++n) {
            #pragma unroll
            for (int c = 0; c < 4; ++c) {
                int off = ((n*16 + lr)*256 + c*64 + lg*16) ^ ((lr & 7) << 4);
                bf16x8 kf = *(const bf16x8*)((char*)Klds + off);
                s[n] = __builtin_amdgcn_mfma_f32_16x16x32_bf16(kf, qf[c], s[n], 0, 0, 0);
            }
        }

        float p[16];
        const bool needmask = (k0 + KVBLK - 1) > (q0w + SP_);
        if (needmask) {
            const int qv = q0w + lr + SP_;
            #pragma unroll
            for (int n = 0; n < 4; ++n)
                #pragma unroll
                for (int r = 0; r < 4; ++r) {
                    int kg = k0 + n*16 + lg*4 + r;
                    p[n*4+r] = (kg <= qv) ? s[n][r] : -1e30f;
                }
        } else {
            #pragma unroll
            for (int n = 0; n < 4; ++n)
                #pragma unroll
                for (int r = 0; r < 4; ++r) p[n*4+r] = s[n][r];
        }

        float mx = p[0];
        #pragma unroll
        for (int i = 1; i < 16; ++i) mx = fmaxf(mx, p[i]);
        mx = fmaxf(mx, __shfl_xor(mx, 16));
        mx = fmaxf(mx, __shfl_xor(mx, 32));
        if (!__all(mx <= m_r + 8.0f)) {
            float mnew  = fmaxf(m_r, mx);
            float alpha = exp2f(m_r - mnew);
            m_r = mnew;
            l_r *= alpha;
            #pragma unroll
            for (int dt = 0; dt < 8; ++dt) {
                o[dt][0] *= alpha; o[dt][1] *= alpha;
                o[dt][2] *= alpha; o[dt][3] *= alpha;
            }
        }
        float psum = 0.f;
        #pragma unroll
        for (int i = 0; i < 16; ++i) { p[i] = exp2f(p[i] - m_r); psum += p[i]; }
        psum += __shfl_xor(psum, 16);
        psum += __shfl_xor(psum, 32);
        l_r += psum;

        char* Pw = (char*)Plds + w*2048;
        #pragma unroll
        for (int n = 0; n < 4; ++n) {
            bf16x4 t;
            t[0]=f2bf(p[n*4+0]); t[1]=f2bf(p[n*4+1]);
            t[2]=f2bf(p[n*4+2]); t[3]=f2bf(p[n*4+3]);
            int off = (lr*128 + n*32 + lg*8) ^ ((lr & 7) << 4);
            *(bf16x4*)(Pw + off) = t;
        }

        #pragma unroll
        for (int kk = 0; kk < 2; ++kk) {
            int poff = (lr*128 + kk*64 + lg*16) ^ ((lr & 7) << 4);
            bf16x8 pa = *(const bf16x8*)(Pw + poff);
            #pragma unroll
            for (int dt = 0; dt < 8; ++dt) {
                int voff = ((dt*16 + lr)*128 + kk*64 + lg*16) ^ ((lr & 7) << 4);
                bf16x8 vf = *(const bf16x8*)((char*)Vlds + voff);
                o[dt] = __builtin_amdgcn_mfma_f32_16x16x32_bf16(vf, pa, o[dt], 0, 0, 0);
            }
        }
    }

    float inv = 1.0f / l_r;
    float* orow = Out + (((size_t)b*H_ + h)*SQ_ + q0w + lr)*(size_t)D_;
    #pragma unroll
    for (int dt = 0; dt < 8; ++dt) {
        f32x4 st;
        st[0]=o[dt][0]*inv; st[1]=o[dt][1]*inv;
        st[2]=o[dt][2]*inv; st[3]=o[dt][3]*inv;
        *(f32x4*)(orow + dt*16 + lg*4) = st;
    }
}

extern "C" void kernel_launch(void* const* d_in, const int* in_sizes, int n_in,
                              void* d_out, int out_size, void* d_ws, size_t ws_size,
                              hipStream_t stream) {
    const float* Q   = (const float*)d_in[0];
    const float* K   = (const float*)d_in[1];
    const float* V   = (const float*)d_in[2];
    const float* PK  = (const float*)d_in[3];
    const float* PV  = (const float*)d_in[4];
    float* out = (float*)d_out;
    float* opk = out + (size_t)B_*H_*SQ_*D_;
    float* opv = opk + (size_t)B_*HKV_*SK_*D_;

    const size_t NEED = (size_t)NTILES * TILEB;   // 20 MB
    if (ws_size >= NEED) {
        char* ws = (char*)d_ws;
        prep_kernel<<<NTILES, 256, 0, stream>>>(K, V, PK, PV, opk, opv, ws);
        attn_lean_kernel<<<512, 256, 0, stream>>>(Q, out, ws);
    } else {
        attn_fallback_kernel<<<576, 256, 0, stream>>>(Q, K, V, PK, PV, out, opk, opv);
    }
}